// Round 2
// baseline (4000.218 us; speedup 1.0000x reference)
//
#include <hip/hip_runtime.h>
#include <hip/hip_bf16.h>
#include <float.h>
#include <math.h>

#define N_NODES 50000
#define N_EDGES 500000
#define D 128
#define ED 10
#define EPS_PNA 1e-5f
#define TE 4    // edges per block tile (one per wave)
#define TN 16   // nodes per block in k_node

typedef __hip_bfloat16 bf16;

__device__ __forceinline__ float u2f(unsigned int u) { return __uint_as_float(u); }

// float atomic max/min via int tricks (valid for mixed signs, init +-FLT_MAX):
__device__ __forceinline__ void atomicMaxF(float* addr, float v) {
    if (v >= 0.f) atomicMax((int*)addr, __float_as_int(v));
    else          atomicMin((unsigned int*)addr, (unsigned int)__float_as_int(v));
}
__device__ __forceinline__ void atomicMinF(float* addr, float v) {
    if (v >= 0.f) atomicMin((int*)addr, __float_as_int(v));
    else          atomicMax((unsigned int*)addr, (unsigned int)__float_as_int(v));
}

// ---------------- K0: init workspace ----------------
__global__ void k_init(float* __restrict__ sum, float* __restrict__ sumsq,
                       float* __restrict__ mx, float* __restrict__ mn,
                       float* __restrict__ cnt, float* __restrict__ avglog) {
    int i = blockIdx.x * blockDim.x + threadIdx.x;
    const int total = N_NODES * D;
    if (i < total) {
        sum[i] = 0.f; sumsq[i] = 0.f;
        mx[i] = -FLT_MAX; mn[i] = FLT_MAX;
    }
    if (i < N_NODES) cnt[i] = 0.f;
    if (i == 0) avglog[0] = 0.f;
}

// ---------------- K1: tiled edge message + atomic scatter ----------------
// 256 threads = 4 waves; wave w handles edge (tile*4 + w); lane l owns feats {2l, 2l+1}.
// W_pre cached in LDS as bf16 (one load per block), read as packed uint (2 feats).
__global__ __launch_bounds__(256) void k_edge(
    const float* __restrict__ x, const float* __restrict__ eattr,
    const float* __restrict__ Wee, const float* __restrict__ bee,
    const float* __restrict__ Wpre, const float* __restrict__ bpre,
    const int* __restrict__ ei,
    float* __restrict__ sum, float* __restrict__ sumsq,
    float* __restrict__ mx, float* __restrict__ mn, float* __restrict__ cnt)
{
    __shared__ bf16  Wp[3 * D * D];          // 98304 B, layout [k][j]
    __shared__ float Wee_s[ED * D];          // 5120 B
    __shared__ float bee_s[D], bpre_s[D];    // 1024 B
    __shared__ float h[TE][3 * D];           // 6144 B
    __shared__ float ea_s[TE][ED];           // 640 B
    __shared__ int   src_s[TE], dst_s[TE];

    const int t = threadIdx.x;
    // one-time weight staging
    for (int i = t; i < 3 * D * D; i += 256) Wp[i] = __float2bfloat16(Wpre[i]);
    for (int i = t; i < ED * D; i += 256)    Wee_s[i] = Wee[i];
    if (t < D) { bee_s[t] = bee[t]; bpre_s[t] = bpre[t]; }
    __syncthreads();

    const int w = t >> 6, l = t & 63;
    const int j0 = 2 * l, j1 = 2 * l + 1;
    const unsigned int* Wpu = (const unsigned int*)Wp;   // dword k*64+l = feats (2l,2l+1) of row k
    const int n_tiles = N_EDGES / TE;

    for (int T = blockIdx.x; T < n_tiles; T += gridDim.x) {
        const int e_base = T * TE;
        if (t < TE * ED) {
            int e = t / ED, k = t % ED;
            ea_s[e][k] = eattr[(size_t)(e_base + e) * ED + k];
        }
        if (t >= 64 && t < 64 + TE)      src_s[t - 64] = ei[e_base + (t - 64)];
        if (t >= 72 && t < 72 + TE)      dst_s[t - 72] = ei[N_EDGES + e_base + (t - 72)];
        __syncthreads();

        // gather x rows + edge encoder (wave w builds h[w])
        {
            const int dst = dst_s[w], src = src_s[w];
            float2 xd = ((const float2*)x)[(size_t)dst * (D / 2) + l];
            float2 xs = ((const float2*)x)[(size_t)src * (D / 2) + l];
            h[w][j0] = xd.x;       h[w][j1] = xd.y;
            h[w][D + j0] = xs.x;   h[w][D + j1] = xs.y;
            float e0 = bee_s[j0], e1 = bee_s[j1];
            #pragma unroll
            for (int k = 0; k < ED; ++k) {
                float a = ea_s[w][k];
                e0 += a * Wee_s[k * D + j0];
                e1 += a * Wee_s[k * D + j1];
            }
            h[w][2 * D + j0] = e0; h[w][2 * D + j1] = e1;
        }
        __syncthreads();

        // pre-MLP GEMM: m_j = bpre_j + sum_k h_k * W[k][j]
        float m0 = bpre_s[j0], m1 = bpre_s[j1];
        float m0b = 0.f, m1b = 0.f;
        #pragma unroll 8
        for (int k = 0; k < 3 * D; k += 2) {
            unsigned int u0 = Wpu[k * 64 + l];
            unsigned int u1 = Wpu[(k + 1) * 64 + l];
            float hv0 = h[w][k], hv1 = h[w][k + 1];
            m0  += hv0 * u2f(u0 << 16);
            m1  += hv0 * u2f(u0 & 0xFFFF0000u);
            m0b += hv1 * u2f(u1 << 16);
            m1b += hv1 * u2f(u1 & 0xFFFF0000u);
        }
        m0 += m0b; m1 += m1b;

        // scatter
        const int dst = dst_s[w];
        const size_t base = (size_t)dst * D + j0;
        atomicAdd(sum + base, m0);         atomicAdd(sum + base + 1, m1);
        atomicAdd(sumsq + base, m0 * m0);  atomicAdd(sumsq + base + 1, m1 * m1);
        atomicMaxF(mx + base, m0);         atomicMaxF(mx + base + 1, m1);
        atomicMinF(mn + base, m0);         atomicMinF(mn + base + 1, m1);
        if (l == 0) atomicAdd(cnt + dst, 1.0f);
        __syncthreads();
    }
}

// ---------------- K2: avg_log = mean over nodes of log(cnt+1) ----------------
__global__ void k_avglog(const float* __restrict__ cnt, float* __restrict__ avglog) {
    int i = blockIdx.x * blockDim.x + threadIdx.x;
    float v = 0.f;
    for (int n = i; n < N_NODES; n += gridDim.x * blockDim.x)
        v += logf(cnt[n] + 1.0f);
    for (int off = 32; off > 0; off >>= 1) v += __shfl_down(v, off, 64);
    __shared__ float wsum[4];
    const int lane = threadIdx.x & 63, wv = threadIdx.x >> 6;
    if (lane == 0) wsum[wv] = v;
    __syncthreads();
    if (threadIdx.x == 0) {
        float tt = 0.f;
        for (int k = 0; k < 4; ++k) tt += wsum[k];
        atomicAdd(avglog, tt);
    }
}

// ---------------- K3: per-node post-MLP + final linear ----------------
// 16 nodes per block; H13 stored transposed [k][node] so the GEMM loop reads
// 8 h-values per float4 broadcast. Weights streamed from L2.
__global__ __launch_bounds__(256) void k_node(
    const float* __restrict__ x,
    const float* __restrict__ Wpost, const float* __restrict__ bpost,
    const float* __restrict__ Wlin, const float* __restrict__ blin,
    const float* __restrict__ sum, const float* __restrict__ sumsq,
    const float* __restrict__ mx, const float* __restrict__ mn,
    const float* __restrict__ cnt, const float* __restrict__ avglog,
    float* __restrict__ out)
{
    __shared__ float h13t[13 * D * TN];   // [k][n], 106496 B
    __shared__ float postT[D * TN];       // [k][n], 8192 B

    const int t = threadIdx.x;
    const int nb = blockIdx.x * TN;
    const float al = avglog[0] * (1.0f / (float)N_NODES);

    // build H13 (transposed)
    for (int i = t; i < TN * D; i += 256) {
        const int n = i >> 7, j = i & (D - 1);
        const int node = nb + n;
        const float c = cnt[node];
        const float deg = fmaxf(c, 1.0f);
        const bool has = (c > 0.f);
        const size_t base = (size_t)node * D + j;
        const float mean = sum[base] / deg;
        const float msq  = sumsq[base] / deg;
        const float stdv = sqrtf(fmaxf(msq - mean * mean, 0.f) + EPS_PNA);
        const float vmx = has ? mx[base] : 0.f;
        const float vmn = has ? mn[base] : 0.f;
        const float sl = logf(deg + 1.0f);
        const float r1 = sl / al, r2 = al / sl;
        h13t[(0 * D + j) * TN + n]  = x[base];
        h13t[(1 * D + j) * TN + n]  = mean;
        h13t[(2 * D + j) * TN + n]  = vmx;
        h13t[(3 * D + j) * TN + n]  = vmn;
        h13t[(4 * D + j) * TN + n]  = stdv;
        h13t[(5 * D + j) * TN + n]  = mean * r1;
        h13t[(6 * D + j) * TN + n]  = vmx * r1;
        h13t[(7 * D + j) * TN + n]  = vmn * r1;
        h13t[(8 * D + j) * TN + n]  = stdv * r1;
        h13t[(9 * D + j) * TN + n]  = mean * r2;
        h13t[(10 * D + j) * TN + n] = vmx * r2;
        h13t[(11 * D + j) * TN + n] = vmn * r2;
        h13t[(12 * D + j) * TN + n] = stdv * r2;
    }
    __syncthreads();

    const int j = t & (D - 1), ng = t >> 7;   // ng in {0,1}: nodes ng*8 .. ng*8+7
    float acc[8] = {0.f};
    #pragma unroll 4
    for (int k = 0; k < 13 * D; ++k) {
        const float wv = Wpost[(size_t)k * D + j];
        const float4 ha = *(const float4*)&h13t[k * TN + ng * 8];
        const float4 hb = *(const float4*)&h13t[k * TN + ng * 8 + 4];
        acc[0] += ha.x * wv; acc[1] += ha.y * wv; acc[2] += ha.z * wv; acc[3] += ha.w * wv;
        acc[4] += hb.x * wv; acc[5] += hb.y * wv; acc[6] += hb.z * wv; acc[7] += hb.w * wv;
    }
    {
        const float b = bpost[j];
        #pragma unroll
        for (int i = 0; i < 8; ++i)
            postT[j * TN + ng * 8 + i] = acc[i] + b;
    }
    __syncthreads();

    float o[8] = {0.f};
    #pragma unroll 4
    for (int k = 0; k < D; ++k) {
        const float wv = Wlin[(size_t)k * D + j];
        const float4 pa = *(const float4*)&postT[k * TN + ng * 8];
        const float4 pb = *(const float4*)&postT[k * TN + ng * 8 + 4];
        o[0] += pa.x * wv; o[1] += pa.y * wv; o[2] += pa.z * wv; o[3] += pa.w * wv;
        o[4] += pb.x * wv; o[5] += pb.y * wv; o[6] += pb.z * wv; o[7] += pb.w * wv;
    }
    {
        const float b = blin[j];
        #pragma unroll
        for (int i = 0; i < 8; ++i)
            out[(size_t)(nb + ng * 8 + i) * D + j] = o[i] + b;
    }
}

extern "C" void kernel_launch(void* const* d_in, const int* in_sizes, int n_in,
                              void* d_out, int out_size, void* d_ws, size_t ws_size,
                              hipStream_t stream) {
    const float* x     = (const float*)d_in[0];
    const float* eattr = (const float*)d_in[1];
    const float* Wee   = (const float*)d_in[2];
    const float* bee   = (const float*)d_in[3];
    const float* Wpre  = (const float*)d_in[4];
    const float* bpre  = (const float*)d_in[5];
    const float* Wpost = (const float*)d_in[6];
    const float* bpost = (const float*)d_in[7];
    const float* Wlin  = (const float*)d_in[8];
    const float* blin  = (const float*)d_in[9];
    const int*   ei    = (const int*)d_in[10];
    float* out = (float*)d_out;

    float* ws    = (float*)d_ws;
    float* sum   = ws;
    float* sumsq = sum   + (size_t)N_NODES * D;
    float* mx    = sumsq + (size_t)N_NODES * D;
    float* mn    = mx    + (size_t)N_NODES * D;
    float* cnt   = mn    + (size_t)N_NODES * D;
    float* avglog = cnt + N_NODES;

    const int initBlocks = (N_NODES * D + 255) / 256;
    k_init<<<initBlocks, 256, 0, stream>>>(sum, sumsq, mx, mn, cnt, avglog);
    k_edge<<<4096, 256, 0, stream>>>(x, eattr, Wee, bee, Wpre, bpre, ei,
                                     sum, sumsq, mx, mn, cnt);
    k_avglog<<<256, 256, 0, stream>>>(cnt, avglog);
    k_node<<<N_NODES / TN, 256, 0, stream>>>(x, Wpost, bpost, Wlin, blin,
                                             sum, sumsq, mx, mn, cnt, avglog, out);
}

// Round 3
// 901.433 us; speedup vs baseline: 4.4376x; 4.4376x over previous
//
#include <hip/hip_runtime.h>
#include <hip/hip_bf16.h>
#include <float.h>
#include <math.h>

#define N_NODES 50000
#define N_EDGES 500000
#define D 128
#define ED 10
#define EPS_PNA 1e-5f

typedef __hip_bfloat16 bf16;

// ---------------- K0: zero degree histogram ----------------
__global__ void k_init(int* __restrict__ cnt) {
    int i = blockIdx.x * blockDim.x + threadIdx.x;
    if (i < N_NODES) cnt[i] = 0;
}

// ---------------- K1: degree histogram ----------------
__global__ void k_hist(const int* __restrict__ ei, int* __restrict__ cnt) {
    int e = blockIdx.x * blockDim.x + threadIdx.x;
    if (e < N_EDGES) atomicAdd(&cnt[ei[N_EDGES + e]], 1);
}

// ---------------- K2: single-block prefix scan over degrees + avg_log ----------------
__global__ __launch_bounds__(1024) void k_scan(const int* __restrict__ cnt,
                                               int* __restrict__ rowstart,
                                               int* __restrict__ cursor,
                                               float* __restrict__ avglog) {
    const int t = threadIdx.x, lane = t & 63, wv = t >> 6;
    __shared__ int wtot[16], woff[16];
    __shared__ int btot_s;
    __shared__ float lred[16];
    int running = 0;
    float lsum = 0.f;
    for (int base = 0; base < N_NODES; base += 1024) {
        const int idx = base + t;
        int c = (idx < N_NODES) ? cnt[idx] : 0;
        if (idx < N_NODES) lsum += logf((float)c + 1.0f);
        // wave-inclusive scan
        int s = c;
        #pragma unroll
        for (int off = 1; off < 64; off <<= 1) {
            int v = __shfl_up(s, off, 64);
            if (lane >= off) s += v;
        }
        if (lane == 63) wtot[wv] = s;
        __syncthreads();
        if (t == 0) {
            int r = 0;
            #pragma unroll
            for (int i = 0; i < 16; ++i) { woff[i] = r; r += wtot[i]; }
            btot_s = r;
        }
        __syncthreads();
        if (idx < N_NODES) {
            const int excl = running + woff[wv] + (s - c);
            rowstart[idx] = excl;
            cursor[idx] = excl;
        }
        running += btot_s;
        __syncthreads();
    }
    if (t == 0) rowstart[N_NODES] = running;
    float v = lsum;
    for (int off = 32; off > 0; off >>= 1) v += __shfl_down(v, off, 64);
    if (lane == 0) lred[wv] = v;
    __syncthreads();
    if (t == 0) {
        float tt = 0.f;
        for (int i = 0; i < 16; ++i) tt += lred[i];
        avglog[0] = tt * (1.0f / (float)N_NODES);
    }
}

// ---------------- K3: bucket edges into CSR order ----------------
__global__ void k_scatter(const int* __restrict__ ei, int* __restrict__ cursor,
                          int* __restrict__ csr_src, int* __restrict__ csr_eid) {
    int e = blockIdx.x * blockDim.x + threadIdx.x;
    if (e < N_EDGES) {
        const int dst = ei[N_EDGES + e];
        const int pos = atomicAdd(&cursor[dst], 1);
        csr_src[pos] = ei[e];
        csr_eid[pos] = e;
    }
}

// ---------------- K4: fold edge-encoder through W3: W4 = Wee@W3, bp = bpre + bee@W3 ----------------
__global__ __launch_bounds__(128) void k_small(const float* __restrict__ Wee,
                                               const float* __restrict__ bee,
                                               const float* __restrict__ Wpre,
                                               const float* __restrict__ bpre,
                                               float* __restrict__ W4,
                                               float* __restrict__ bp) {
    __shared__ float wee_s[ED * D];
    __shared__ float bee_s[D];
    const int t = threadIdx.x;
    for (int i = t; i < ED * D; i += 128) wee_s[i] = Wee[i];
    bee_s[t] = bee[t];
    __syncthreads();
    float acc[ED];
    #pragma unroll
    for (int r = 0; r < ED; ++r) acc[r] = 0.f;
    float bacc = 0.f;
    for (int k = 0; k < D; ++k) {
        const float w3 = Wpre[(size_t)(2 * D + k) * D + t];
        #pragma unroll
        for (int r = 0; r < ED; ++r) acc[r] += wee_s[r * D + k] * w3;
        bacc += bee_s[k] * w3;
    }
    #pragma unroll
    for (int r = 0; r < ED; ++r) W4[r * D + t] = acc[r];
    bp[t] = bpre[t] + bacc;
}

// ---------------- K5: node-level GEMMs  Y1 = x@W1, Y2 = x@W2 ----------------
// 16 nodes/block; x tile transposed in LDS; weights streamed from L2.
__global__ __launch_bounds__(256) void k_y12(const float* __restrict__ x,
                                             const float* __restrict__ Wpre,
                                             float* __restrict__ Y1,
                                             float* __restrict__ Y2) {
    __shared__ float xT[D][20];   // [k][n], pad 16->20 (16B-aligned rows)
    const int t = threadIdx.x;
    const int nb = blockIdx.x * 16;
    for (int i = t; i < 16 * D; i += 256) {
        const int n = i >> 7, k = i & (D - 1);
        xT[k][n] = x[(size_t)(nb + n) * D + k];
    }
    __syncthreads();
    const int j = t & (D - 1), ng = t >> 7;
    float a1[8], a2[8];
    #pragma unroll
    for (int i = 0; i < 8; ++i) { a1[i] = 0.f; a2[i] = 0.f; }
    #pragma unroll 4
    for (int k = 0; k < D; ++k) {
        const float w1 = Wpre[(size_t)k * D + j];
        const float w2 = Wpre[(size_t)(D + k) * D + j];
        const float4 ha = *(const float4*)&xT[k][ng * 8];
        const float4 hb = *(const float4*)&xT[k][ng * 8 + 4];
        a1[0] += ha.x * w1; a1[1] += ha.y * w1; a1[2] += ha.z * w1; a1[3] += ha.w * w1;
        a1[4] += hb.x * w1; a1[5] += hb.y * w1; a1[6] += hb.z * w1; a1[7] += hb.w * w1;
        a2[0] += ha.x * w2; a2[1] += ha.y * w2; a2[2] += ha.z * w2; a2[3] += ha.w * w2;
        a2[4] += hb.x * w2; a2[5] += hb.y * w2; a2[6] += hb.z * w2; a2[7] += hb.w * w2;
    }
    #pragma unroll
    for (int i = 0; i < 8; ++i) {
        const size_t row = (size_t)(nb + ng * 8 + i) * D + j;
        Y1[row] = a1[i];
        Y2[row] = a2[i];
    }
}

// ---------------- K6: CSR pull aggregation (one wave per node) ----------------
// z = Y2[src] + eattr@W4; aggregate z; shift mean/max/min by c = Y1[n] + bp.
// Writes mean (fp32, over Y1) and mx/mn/std (bf16).
__global__ __launch_bounds__(256) void k_pull(
    const float* __restrict__ eattr, const float* __restrict__ W4,
    const float* __restrict__ bp, float* Y1mean,
    const float* __restrict__ Y2,
    const int* __restrict__ rowstart,
    const int* __restrict__ csr_src, const int* __restrict__ csr_eid,
    bf16* __restrict__ mxB, bf16* __restrict__ mnB, bf16* __restrict__ stB)
{
    __shared__ float2 w4s[ED][64];
    const int t = threadIdx.x;
    for (int i = t; i < ED * 64; i += 256)
        w4s[i >> 6][i & 63] = ((const float2*)W4)[i];
    __syncthreads();

    const int wv = t >> 6, l = t & 63;
    const int n = blockIdx.x * 4 + wv;
    const int r0 = rowstart[n], r1 = rowstart[n + 1];

    float s0 = 0.f, s1 = 0.f, ss0 = 0.f, ss1 = 0.f;
    float mx0 = -FLT_MAX, mx1 = -FLT_MAX, mn0 = FLT_MAX, mn1 = FLT_MAX;
    for (int i = r0; i < r1; ++i) {
        const int src = csr_src[i];
        const int eid = csr_eid[i];
        const float2 y2 = ((const float2*)Y2)[(size_t)src * 64 + l];
        const float2* ea2 = (const float2*)(eattr + (size_t)eid * ED);
        float q0 = 0.f, q1 = 0.f;
        #pragma unroll
        for (int r = 0; r < 5; ++r) {
            const float2 a = ea2[r];
            const float2 wA = w4s[2 * r][l];
            const float2 wB = w4s[2 * r + 1][l];
            q0 += a.x * wA.x + a.y * wB.x;
            q1 += a.x * wA.y + a.y * wB.y;
        }
        const float z0 = y2.x + q0, z1 = y2.y + q1;
        s0 += z0; s1 += z1;
        ss0 += z0 * z0; ss1 += z1 * z1;
        mx0 = fmaxf(mx0, z0); mx1 = fmaxf(mx1, z1);
        mn0 = fminf(mn0, z0); mn1 = fminf(mn1, z1);
    }
    const int d = r1 - r0;
    const float2 bpw = ((const float2*)bp)[l];
    const float2 y1 = ((const float2*)Y1mean)[(size_t)n * 64 + l];
    float mean0, mean1, vmx0, vmx1, vmn0, vmn1, st0, st1;
    if (d > 0) {
        const float inv = 1.f / (float)d;
        const float mz0 = s0 * inv, mz1 = s1 * inv;
        const float c0 = y1.x + bpw.x, c1 = y1.y + bpw.y;
        mean0 = mz0 + c0; mean1 = mz1 + c1;
        st0 = sqrtf(fmaxf(ss0 * inv - mz0 * mz0, 0.f) + EPS_PNA);
        st1 = sqrtf(fmaxf(ss1 * inv - mz1 * mz1, 0.f) + EPS_PNA);
        vmx0 = mx0 + c0; vmx1 = mx1 + c1;
        vmn0 = mn0 + c0; vmn1 = mn1 + c1;
    } else {
        mean0 = mean1 = 0.f;
        vmx0 = vmx1 = vmn0 = vmn1 = 0.f;
        st0 = st1 = sqrtf(EPS_PNA);
    }
    ((float2*)Y1mean)[(size_t)n * 64 + l] = make_float2(mean0, mean1);
    __hip_bfloat162 h;
    h.x = __float2bfloat16(vmx0); h.y = __float2bfloat16(vmx1);
    ((__hip_bfloat162*)mxB)[(size_t)n * 64 + l] = h;
    h.x = __float2bfloat16(vmn0); h.y = __float2bfloat16(vmn1);
    ((__hip_bfloat162*)mnB)[(size_t)n * 64 + l] = h;
    h.x = __float2bfloat16(st0);  h.y = __float2bfloat16(st1);
    ((__hip_bfloat162*)stB)[(size_t)n * 64 + l] = h;
}

// ---------------- K7: post-MLP + final linear (8 nodes/block) ----------------
__global__ __launch_bounds__(256) void k_node(
    const float* __restrict__ x,
    const float* __restrict__ Wpost, const float* __restrict__ bpost,
    const float* __restrict__ Wlin, const float* __restrict__ blin,
    const float* __restrict__ meanA, const bf16* __restrict__ mxB,
    const bf16* __restrict__ mnB, const bf16* __restrict__ stB,
    const int* __restrict__ cnt, const float* __restrict__ avglog,
    float* __restrict__ out)
{
    __shared__ float h13t[13 * D][8];   // [k][n], 53248 B
    __shared__ float postT[D][8];       // 4096 B
    const int t = threadIdx.x;
    const int nb = blockIdx.x * 8;
    const float al = avglog[0];

    for (int i = t; i < 8 * D; i += 256) {
        const int n = i >> 7, j = i & (D - 1);
        const int node = nb + n;
        const float deg = fmaxf((float)cnt[node], 1.f);
        const size_t base = (size_t)node * D + j;
        const float mean = meanA[base];
        const float vmx = __bfloat162float(mxB[base]);
        const float vmn = __bfloat162float(mnB[base]);
        const float stdv = __bfloat162float(stB[base]);
        const float sl = logf(deg + 1.f);
        const float r1 = sl / al, r2 = al / sl;
        h13t[0 * D + j][n]  = x[base];
        h13t[1 * D + j][n]  = mean;
        h13t[2 * D + j][n]  = vmx;
        h13t[3 * D + j][n]  = vmn;
        h13t[4 * D + j][n]  = stdv;
        h13t[5 * D + j][n]  = mean * r1;
        h13t[6 * D + j][n]  = vmx * r1;
        h13t[7 * D + j][n]  = vmn * r1;
        h13t[8 * D + j][n]  = stdv * r1;
        h13t[9 * D + j][n]  = mean * r2;
        h13t[10 * D + j][n] = vmx * r2;
        h13t[11 * D + j][n] = vmn * r2;
        h13t[12 * D + j][n] = stdv * r2;
    }
    __syncthreads();

    const int j = t & (D - 1), ng = t >> 7;
    float acc[4] = {0.f, 0.f, 0.f, 0.f};
    #pragma unroll 8
    for (int k = 0; k < 13 * D; ++k) {
        const float wv = Wpost[(size_t)k * D + j];
        const float4 hh = *(const float4*)&h13t[k][ng * 4];
        acc[0] += hh.x * wv; acc[1] += hh.y * wv; acc[2] += hh.z * wv; acc[3] += hh.w * wv;
    }
    {
        const float b = bpost[j];
        *(float4*)&postT[j][ng * 4] =
            make_float4(acc[0] + b, acc[1] + b, acc[2] + b, acc[3] + b);
    }
    __syncthreads();

    float o[4] = {0.f, 0.f, 0.f, 0.f};
    #pragma unroll 8
    for (int k = 0; k < D; ++k) {
        const float wv = Wlin[(size_t)k * D + j];
        const float4 pp = *(const float4*)&postT[k][ng * 4];
        o[0] += pp.x * wv; o[1] += pp.y * wv; o[2] += pp.z * wv; o[3] += pp.w * wv;
    }
    {
        const float b = blin[j];
        #pragma unroll
        for (int i = 0; i < 4; ++i)
            out[(size_t)(nb + ng * 4 + i) * D + j] = o[i] + b;
    }
}

extern "C" void kernel_launch(void* const* d_in, const int* in_sizes, int n_in,
                              void* d_out, int out_size, void* d_ws, size_t ws_size,
                              hipStream_t stream) {
    const float* x     = (const float*)d_in[0];
    const float* eattr = (const float*)d_in[1];
    const float* Wee   = (const float*)d_in[2];
    const float* bee   = (const float*)d_in[3];
    const float* Wpre  = (const float*)d_in[4];
    const float* bpre  = (const float*)d_in[5];
    const float* Wpost = (const float*)d_in[6];
    const float* bpost = (const float*)d_in[7];
    const float* Wlin  = (const float*)d_in[8];
    const float* blin  = (const float*)d_in[9];
    const int*   ei    = (const int*)d_in[10];
    float* out = (float*)d_out;

    // workspace layout (94.2 MB total; proven ws_size >= 103 MB)
    float* Y1   = (float*)d_ws;                       // N*D fp32 (aliased: mean after k_pull)
    float* Y2   = Y1 + (size_t)N_NODES * D;           // N*D fp32
    bf16*  mxB  = (bf16*)(Y2 + (size_t)N_NODES * D);  // N*D bf16
    bf16*  mnB  = mxB + (size_t)N_NODES * D;
    bf16*  stB  = mnB + (size_t)N_NODES * D;
    int*   cnt      = (int*)(stB + (size_t)N_NODES * D);
    int*   rowstart = cnt + N_NODES;                  // N+1 (+1 pad for alignment)
    int*   cursor   = rowstart + N_NODES + 2;
    int*   csr_src  = cursor + N_NODES;
    int*   csr_eid  = csr_src + N_EDGES;
    float* W4   = (float*)(csr_eid + N_EDGES);        // ED*D
    float* bp   = W4 + ED * D;                        // D
    float* avglog = bp + D;                           // 1

    k_init<<<(N_NODES + 255) / 256, 256, 0, stream>>>(cnt);
    k_hist<<<(N_EDGES + 255) / 256, 256, 0, stream>>>(ei, cnt);
    k_scan<<<1, 1024, 0, stream>>>(cnt, rowstart, cursor, avglog);
    k_scatter<<<(N_EDGES + 255) / 256, 256, 0, stream>>>(ei, cursor, csr_src, csr_eid);
    k_small<<<1, 128, 0, stream>>>(Wee, bee, Wpre, bpre, W4, bp);
    k_y12<<<N_NODES / 16, 256, 0, stream>>>(x, Wpre, Y1, Y2);
    k_pull<<<N_NODES / 4, 256, 0, stream>>>(eattr, W4, bp, Y1, Y2,
                                            rowstart, csr_src, csr_eid, mxB, mnB, stB);
    k_node<<<N_NODES / 8, 256, 0, stream>>>(x, Wpost, bpost, Wlin, blin,
                                            Y1, mxB, mnB, stB, cnt, avglog, out);
}

// Round 5
// 452.989 us; speedup vs baseline: 8.8307x; 1.9900x over previous
//
#include <hip/hip_runtime.h>
#include <hip/hip_bf16.h>
#include <float.h>
#include <math.h>

#define N_NODES 50000
#define N_EDGES 500000
#define D 128
#define ED 10
#define EPS_PNA 1e-5f

typedef __hip_bfloat16 bf16;
typedef unsigned short ushort;
typedef unsigned int uint;
typedef __attribute__((ext_vector_type(8))) short short8;   // 8 bf16 (4 VGPRs)
typedef __attribute__((ext_vector_type(4))) float f32x4;    // MFMA C/D

__device__ __forceinline__ ushort f2bf(float f) {
    __hip_bfloat16 h = __float2bfloat16(f);
    return *reinterpret_cast<ushort*>(&h);
}
__device__ __forceinline__ float bf2f(ushort u) {
    return __uint_as_float(((uint)u) << 16);
}

// ---------------- K0: zero degree histogram ----------------
__global__ void k_init(int* __restrict__ cnt) {
    int i = blockIdx.x * blockDim.x + threadIdx.x;
    if (i < N_NODES) cnt[i] = 0;
}

// ---------------- K1: degree histogram ----------------
__global__ void k_hist(const int* __restrict__ ei, int* __restrict__ cnt) {
    int e = blockIdx.x * blockDim.x + threadIdx.x;
    if (e < N_EDGES) atomicAdd(&cnt[ei[N_EDGES + e]], 1);
}

// ---------------- K2: single-block prefix scan over degrees + avg_log ----------------
__global__ __launch_bounds__(1024) void k_scan(const int* __restrict__ cnt,
                                               int* __restrict__ rowstart,
                                               int* __restrict__ cursor,
                                               float* __restrict__ avglog) {
    const int t = threadIdx.x, lane = t & 63, wv = t >> 6;
    __shared__ int wtot[16], woff[16];
    __shared__ int btot_s;
    __shared__ float lred[16];
    int running = 0;
    float lsum = 0.f;
    for (int base = 0; base < N_NODES; base += 1024) {
        const int idx = base + t;
        int c = (idx < N_NODES) ? cnt[idx] : 0;
        if (idx < N_NODES) lsum += logf((float)c + 1.0f);
        int s = c;
        #pragma unroll
        for (int off = 1; off < 64; off <<= 1) {
            int v = __shfl_up(s, off, 64);
            if (lane >= off) s += v;
        }
        if (lane == 63) wtot[wv] = s;
        __syncthreads();
        if (t == 0) {
            int r = 0;
            #pragma unroll
            for (int i = 0; i < 16; ++i) { woff[i] = r; r += wtot[i]; }
            btot_s = r;
        }
        __syncthreads();
        if (idx < N_NODES) {
            const int excl = running + woff[wv] + (s - c);
            rowstart[idx] = excl;
            cursor[idx] = excl;
        }
        running += btot_s;
        __syncthreads();
    }
    if (t == 0) rowstart[N_NODES] = running;
    float v = lsum;
    for (int off = 32; off > 0; off >>= 1) v += __shfl_down(v, off, 64);
    if (lane == 0) lred[wv] = v;
    __syncthreads();
    if (t == 0) {
        float tt = 0.f;
        for (int i = 0; i < 16; ++i) tt += lred[i];
        avglog[0] = tt * (1.0f / (float)N_NODES);
    }
}

// ---------------- K3: bucket edges into CSR order ----------------
__global__ void k_scatter(const int* __restrict__ ei, int* __restrict__ cursor,
                          int* __restrict__ csr_src, int* __restrict__ csr_eid) {
    int e = blockIdx.x * blockDim.x + threadIdx.x;
    if (e < N_EDGES) {
        const int dst = ei[N_EDGES + e];
        const int pos = atomicAdd(&cursor[dst], 1);
        csr_src[pos] = ei[e];
        csr_eid[pos] = e;
    }
}

// ---------------- K4: fold edge-encoder through W3 ----------------
__global__ __launch_bounds__(128) void k_small(const float* __restrict__ Wee,
                                               const float* __restrict__ bee,
                                               const float* __restrict__ Wpre,
                                               const float* __restrict__ bpre,
                                               float* __restrict__ W4,
                                               float* __restrict__ bp) {
    __shared__ float wee_s[ED * D];
    __shared__ float bee_s[D];
    const int t = threadIdx.x;
    for (int i = t; i < ED * D; i += 128) wee_s[i] = Wee[i];
    bee_s[t] = bee[t];
    __syncthreads();
    float acc[ED];
    #pragma unroll
    for (int r = 0; r < ED; ++r) acc[r] = 0.f;
    float bacc = 0.f;
    for (int k = 0; k < D; ++k) {
        const float w3 = Wpre[(size_t)(2 * D + k) * D + t];
        #pragma unroll
        for (int r = 0; r < ED; ++r) acc[r] += wee_s[r * D + k] * w3;
        bacc += bee_s[k] * w3;
    }
    #pragma unroll
    for (int r = 0; r < ED; ++r) W4[r * D + t] = acc[r];
    bp[t] = bpre[t] + bacc;
}

// ---------------- K5: transpose weight [K][128] fp32 -> [128][K] bf16 ----------------
__global__ void k_prep(const float* __restrict__ src, ushort* __restrict__ dst,
                       int K, int jobs) {
    int id = blockIdx.x * blockDim.x + threadIdx.x;
    if (id >= jobs) return;
    const int col = id & 127;
    const int k0 = (id >> 7) * 8;
    ushort tmp[8];
    #pragma unroll
    for (int r = 0; r < 8; ++r) tmp[r] = f2bf(src[(size_t)(k0 + r) * 128 + col]);
    *(uint4*)(dst + (size_t)col * K + k0) = *(uint4*)tmp;
}

// ---------------- K6: cast x to bf16 ----------------
__global__ void k_cast(const float* __restrict__ x, ushort* __restrict__ xb) {
    int i = blockIdx.x * blockDim.x + threadIdx.x;
    if (i < N_NODES * 64) {
        float2 v = ((const float2*)x)[i];
        ((__hip_bfloat162*)xb)[i] = __float22bfloat162_rn(v);
    }
}

// ---------------- K7: node-level GEMMs  Y1 = x@W1, Y2 = x@W2 (bf16 out) ----------------
__global__ __launch_bounds__(256) void k_y12(const float* __restrict__ x,
                                             const float* __restrict__ Wpre,
                                             ushort* __restrict__ Y1b,
                                             ushort* __restrict__ Y2b) {
    __shared__ float xT[D][20];
    const int t = threadIdx.x;
    const int nb = blockIdx.x * 16;
    for (int i = t; i < 16 * D; i += 256) {
        const int n = i >> 7, k = i & (D - 1);
        xT[k][n] = x[(size_t)(nb + n) * D + k];
    }
    __syncthreads();
    const int j = t & (D - 1), ng = t >> 7;
    float a1[8], a2[8];
    #pragma unroll
    for (int i = 0; i < 8; ++i) { a1[i] = 0.f; a2[i] = 0.f; }
    #pragma unroll 4
    for (int k = 0; k < D; ++k) {
        const float w1 = Wpre[(size_t)k * D + j];
        const float w2 = Wpre[(size_t)(D + k) * D + j];
        const float4 ha = *(const float4*)&xT[k][ng * 8];
        const float4 hb = *(const float4*)&xT[k][ng * 8 + 4];
        a1[0] += ha.x * w1; a1[1] += ha.y * w1; a1[2] += ha.z * w1; a1[3] += ha.w * w1;
        a1[4] += hb.x * w1; a1[5] += hb.y * w1; a1[6] += hb.z * w1; a1[7] += hb.w * w1;
        a2[0] += ha.x * w2; a2[1] += ha.y * w2; a2[2] += ha.z * w2; a2[3] += ha.w * w2;
        a2[4] += hb.x * w2; a2[5] += hb.y * w2; a2[6] += hb.z * w2; a2[7] += hb.w * w2;
    }
    #pragma unroll
    for (int i = 0; i < 8; ++i) {
        const size_t row = (size_t)(nb + ng * 8 + i) * D + j;
        Y1b[row] = f2bf(a1[i]);
        Y2b[row] = f2bf(a2[i]);
    }
}

// ---------------- K8: CSR pull aggregation -> agg bf16 [N][512] ----------------
__global__ __launch_bounds__(256) void k_pull(
    const float* __restrict__ eattr, const float* __restrict__ W4,
    const float* __restrict__ bp, const ushort* __restrict__ Y1b,
    const ushort* __restrict__ Y2b,
    const int* __restrict__ rowstart,
    const int* __restrict__ csr_src, const int* __restrict__ csr_eid,
    ushort* __restrict__ aggB)
{
    __shared__ float2 w4s[ED][64];
    const int t = threadIdx.x;
    for (int i = t; i < ED * 64; i += 256)
        w4s[i >> 6][i & 63] = ((const float2*)W4)[i];
    __syncthreads();

    const int wv = t >> 6, l = t & 63;
    const int n = blockIdx.x * 4 + wv;
    const int r0 = rowstart[n], r1 = rowstart[n + 1];

    float s0 = 0.f, s1 = 0.f, ss0 = 0.f, ss1 = 0.f;
    float mx0 = -FLT_MAX, mx1 = -FLT_MAX, mn0 = FLT_MAX, mn1 = FLT_MAX;
    for (int i = r0; i < r1; ++i) {
        const int src = csr_src[i];
        const int eid = csr_eid[i];
        const float2 y2 = __bfloat1622float2(((const __hip_bfloat162*)Y2b)[(size_t)src * 64 + l]);
        const float2* ea2 = (const float2*)(eattr + (size_t)eid * ED);
        float q0 = 0.f, q1 = 0.f;
        #pragma unroll
        for (int r = 0; r < 5; ++r) {
            const float2 a = ea2[r];
            const float2 wA = w4s[2 * r][l];
            const float2 wB = w4s[2 * r + 1][l];
            q0 += a.x * wA.x + a.y * wB.x;
            q1 += a.x * wA.y + a.y * wB.y;
        }
        const float z0 = y2.x + q0, z1 = y2.y + q1;
        s0 += z0; s1 += z1;
        ss0 += z0 * z0; ss1 += z1 * z1;
        mx0 = fmaxf(mx0, z0); mx1 = fmaxf(mx1, z1);
        mn0 = fminf(mn0, z0); mn1 = fminf(mn1, z1);
    }
    const int d = r1 - r0;
    const float2 bpw = ((const float2*)bp)[l];
    const float2 y1 = __bfloat1622float2(((const __hip_bfloat162*)Y1b)[(size_t)n * 64 + l]);
    float mean0, mean1, vmx0, vmx1, vmn0, vmn1, st0, st1;
    if (d > 0) {
        const float inv = 1.f / (float)d;
        const float mz0 = s0 * inv, mz1 = s1 * inv;
        const float c0 = y1.x + bpw.x, c1 = y1.y + bpw.y;
        mean0 = mz0 + c0; mean1 = mz1 + c1;
        st0 = sqrtf(fmaxf(ss0 * inv - mz0 * mz0, 0.f) + EPS_PNA);
        st1 = sqrtf(fmaxf(ss1 * inv - mz1 * mz1, 0.f) + EPS_PNA);
        vmx0 = mx0 + c0; vmx1 = mx1 + c1;
        vmn0 = mn0 + c0; vmn1 = mn1 + c1;
    } else {
        mean0 = mean1 = 0.f;
        vmx0 = vmx1 = vmn0 = vmn1 = 0.f;
        st0 = st1 = sqrtf(EPS_PNA);
    }
    __hip_bfloat162* aggv = (__hip_bfloat162*)aggB;
    const size_t b0 = (size_t)n * 256;
    aggv[b0 + l]       = __float22bfloat162_rn(make_float2(mean0, mean1));
    aggv[b0 + 64 + l]  = __float22bfloat162_rn(make_float2(vmx0, vmx1));
    aggv[b0 + 128 + l] = __float22bfloat162_rn(make_float2(vmn0, vmn1));
    aggv[b0 + 192 + l] = __float22bfloat162_rn(make_float2(st0, st1));
}

// ---------------- K9: MFMA GEMM1: hpost[n][m] = bpost[m] + sum_k H[n][k]*Wt[m][k] ----------------
// 256 threads = 4 waves (2x2 tiling of 128 outcols x 128 nodes). K = 1664 in 26 chunks of 64.
// H = [xb | agg | r1*agg | r2*agg] staged per chunk; padded rows zero-filled.
__global__ __launch_bounds__(256) void k_node(
    const ushort* __restrict__ Wt,   // [128][1664] bf16
    const ushort* __restrict__ xb,   // [N][128]    bf16
    const ushort* __restrict__ aggB, // [N][512]    bf16
    const float* __restrict__ bpost,
    const int* __restrict__ cnt, const float* __restrict__ avglog,
    ushort* __restrict__ hpostB)     // [N][128]    bf16
{
    __shared__ __align__(16) ushort Alds[128 * 72];
    __shared__ __align__(16) ushort Hlds[128 * 72];
    __shared__ float r1s[128], r2s[128], bpost_s[128];

    const int t = threadIdx.x;
    const int nb = blockIdx.x * 128;

    if (t < 128) {
        bpost_s[t] = bpost[t];
        const int node = nb + t;
        float deg = 1.f;
        if (node < N_NODES) deg = fmaxf((float)cnt[node], 1.f);
        const float sl = logf(deg + 1.f);
        const float al = avglog[0];
        r1s[t] = sl / al;
        r2s[t] = al / sl;
    }
    __syncthreads();

    const int w = t >> 6, l = t & 63;
    const int wr = w >> 1, wc = w & 1;   // wr: outcol half, wc: node half
    const int quad = l >> 4, lr = l & 15;
    const int kk = (t & 7) * 8;          // K offset within 64-chunk for staging

    f32x4 acc[4][4];
    #pragma unroll
    for (int i = 0; i < 4; ++i)
        #pragma unroll
        for (int j = 0; j < 4; ++j) acc[i][j] = (f32x4){0.f, 0.f, 0.f, 0.f};

    for (int kc = 0; kc < 26; ++kc) {
        const int k0 = kc * 64;
        #pragma unroll
        for (int g = 0; g < 4; ++g) {
            const int rowid = (t + g * 256) >> 3;   // [0,128)
            // A: Wpost^T row = outcol
            const uint4 va = *(const uint4*)(Wt + (size_t)rowid * 1664 + k0 + kk);
            *(uint4*)&Alds[rowid * 72 + kk] = va;
            // H: row = node
            const int node = nb + rowid;
            uint4 v = make_uint4(0u, 0u, 0u, 0u);
            if (node < N_NODES) {
                if (kc < 2) {
                    v = *(const uint4*)(xb + (size_t)node * 128 + k0 + kk);
                } else if (kc < 10) {
                    v = *(const uint4*)(aggB + (size_t)node * 512 + (k0 - 128) + kk);
                } else {
                    const int off = (kc < 18) ? (k0 - 640) : (k0 - 1152);
                    const float r = (kc < 18) ? r1s[rowid] : r2s[rowid];
                    v = *(const uint4*)(aggB + (size_t)node * 512 + off + kk);
                    ushort* p = (ushort*)&v;
                    #pragma unroll
                    for (int q = 0; q < 8; ++q) p[q] = f2bf(bf2f(p[q]) * r);
                }
            }
            *(uint4*)&Hlds[rowid * 72 + kk] = v;
        }
        __syncthreads();
        #pragma unroll
        for (int s = 0; s < 2; ++s) {
            short8 av[4], bv[4];
            #pragma unroll
            for (int i = 0; i < 4; ++i)
                av[i] = *(const short8*)&Alds[(wr * 64 + i * 16 + lr) * 72 + s * 32 + quad * 8];
            #pragma unroll
            for (int j = 0; j < 4; ++j)
                bv[j] = *(const short8*)&Hlds[(wc * 64 + j * 16 + lr) * 72 + s * 32 + quad * 8];
            #pragma unroll
            for (int i = 0; i < 4; ++i)
                #pragma unroll
                for (int j = 0; j < 4; ++j)
                    acc[i][j] = __builtin_amdgcn_mfma_f32_16x16x32_bf16(av[i], bv[j], acc[i][j], 0, 0, 0);
        }
        __syncthreads();
    }

    // epilogue: D[m=outcol][n=node]: outcol = quad*4+reg, node = lr (per 16x16 tile)
    #pragma unroll
    for (int i = 0; i < 4; ++i) {
        const int col = wr * 64 + i * 16 + quad * 4;
        const float b0 = bpost_s[col], b1 = bpost_s[col + 1];
        const float b2 = bpost_s[col + 2], b3 = bpost_s[col + 3];
        #pragma unroll
        for (int j = 0; j < 4; ++j) {
            const int node = nb + wc * 64 + j * 16 + lr;
            if (node < N_NODES) {
                const f32x4 v = acc[i][j];
                ushort pk[4];
                pk[0] = f2bf(v.x + b0); pk[1] = f2bf(v.y + b1);
                pk[2] = f2bf(v.z + b2); pk[3] = f2bf(v.w + b3);
                *(uint2*)(hpostB + (size_t)node * 128 + col) = *(uint2*)pk;
            }
        }
    }
}

// ---------------- K10: MFMA GEMM2: out = hpost @ Wlin + blin ----------------
__global__ __launch_bounds__(256) void k_lin(
    const ushort* __restrict__ hpostB,  // [N][128] bf16
    const ushort* __restrict__ Wlt,     // [128][128] bf16 (transposed)
    const float* __restrict__ blin,
    float* __restrict__ out)
{
    __shared__ __align__(16) ushort Hl[128 * 136];
    __shared__ float blin_s[128];
    const int t = threadIdx.x;
    const int nb = blockIdx.x * 128;
    if (t < 128) blin_s[t] = blin[t];
    for (int i = t; i < 2048; i += 256) {
        const int row = i >> 4;             // node row [0,128)
        const int kk = (i & 15) * 8;        // K offset [0,128)
        const int node = nb + row;
        uint4 v = make_uint4(0u, 0u, 0u, 0u);
        if (node < N_NODES) v = *(const uint4*)(hpostB + (size_t)node * 128 + kk);
        *(uint4*)&Hl[row * 136 + kk] = v;
    }
    __syncthreads();

    const int w = t >> 6, l = t & 63;
    const int wr = w >> 1, wc = w & 1;
    const int quad = l >> 4, lr = l & 15;

    f32x4 acc[4][4];
    #pragma unroll
    for (int i = 0; i < 4; ++i)
        #pragma unroll
        for (int j = 0; j < 4; ++j) acc[i][j] = (f32x4){0.f, 0.f, 0.f, 0.f};

    #pragma unroll
    for (int s = 0; s < 4; ++s) {
        short8 av[4], bv[4];
        #pragma unroll
        for (int i = 0; i < 4; ++i)
            av[i] = *(const short8*)(Wlt + (size_t)(wr * 64 + i * 16 + lr) * 128 + s * 32 + quad * 8);
        #pragma unroll
        for (int j = 0; j < 4; ++j)
            bv[j] = *(const short8*)&Hl[(wc * 64 + j * 16 + lr) * 136 + s * 32 + quad * 8];
        #pragma unroll
        for (int i = 0; i < 4; ++i)
            #pragma unroll
            for (int j = 0; j < 4; ++j)
                acc[i][j] = __builtin_amdgcn_mfma_f32_16x16x32_bf16(av[i], bv[j], acc[i][j], 0, 0, 0);
    }

    #pragma unroll
    for (int i = 0; i < 4; ++i) {
        const int col = wr * 64 + i * 16 + quad * 4;
        const float b0 = blin_s[col], b1 = blin_s[col + 1];
        const float b2 = blin_s[col + 2], b3 = blin_s[col + 3];
        #pragma unroll
        for (int j = 0; j < 4; ++j) {
            const int node = nb + wc * 64 + j * 16 + lr;
            if (node < N_NODES) {
                const f32x4 v = acc[i][j];
                *(float4*)(out + (size_t)node * 128 + col) =
                    make_float4(v.x + b0, v.y + b1, v.z + b2, v.w + b3);
            }
        }
    }
}

extern "C" void kernel_launch(void* const* d_in, const int* in_sizes, int n_in,
                              void* d_out, int out_size, void* d_ws, size_t ws_size,
                              hipStream_t stream) {
    const float* x     = (const float*)d_in[0];
    const float* eattr = (const float*)d_in[1];
    const float* Wee   = (const float*)d_in[2];
    const float* bee   = (const float*)d_in[3];
    const float* Wpre  = (const float*)d_in[4];
    const float* bpre  = (const float*)d_in[5];
    const float* Wpost = (const float*)d_in[6];
    const float* bpost = (const float*)d_in[7];
    const float* Wlin  = (const float*)d_in[8];
    const float* blin  = (const float*)d_in[9];
    const int*   ei    = (const int*)d_in[10];
    float* out = (float*)d_out;

    // workspace layout (~94.7 MB; ws_size >= 102.6 MB proven by round-2 run)
    ushort* aggB = (ushort*)d_ws;                         // N*512 bf16
    ushort* xb   = aggB + (size_t)N_NODES * 512;          // N*128 bf16
    ushort* Y1b  = xb   + (size_t)N_NODES * 128;          // N*128 bf16 (reused as hpostB after k_pull)
    ushort* Y2b  = Y1b  + (size_t)N_NODES * 128;          // N*128 bf16
    ushort* Wt   = Y2b  + (size_t)N_NODES * 128;          // 128*1664 bf16
    ushort* Wlt  = Wt + 128 * 1664;                       // 128*128 bf16
    float*  W4   = (float*)(Wlt + 128 * 128);             // ED*D fp32
    float*  bp   = W4 + ED * D;                           // D
    float*  avglog = bp + D;                              // 1 (+pad 3)
    int*   cnt      = (int*)(avglog + 4);
    int*   rowstart = cnt + N_NODES;
    int*   cursor   = rowstart + N_NODES + 2;
    int*   csr_src  = cursor + N_NODES;
    int*   csr_eid  = csr_src + N_EDGES;
    ushort* hpostB = Y1b;   // alias: Y1b dead after k_pull

    k_init<<<(N_NODES + 255) / 256, 256, 0, stream>>>(cnt);
    k_hist<<<(N_EDGES + 255) / 256, 256, 0, stream>>>(ei, cnt);
    k_scan<<<1, 1024, 0, stream>>>(cnt, rowstart, cursor, avglog);
    k_scatter<<<(N_EDGES + 255) / 256, 256, 0, stream>>>(ei, cursor, csr_src, csr_eid);
    k_small<<<1, 128, 0, stream>>>(Wee, bee, Wpre, bpre, W4, bp);
    k_prep<<<104, 256, 0, stream>>>(Wpost, Wt, 1664, (1664 / 8) * 128);
    k_prep<<<8, 256, 0, stream>>>(Wlin, Wlt, 128, (128 / 8) * 128);
    k_cast<<<(N_NODES * 64 + 255) / 256, 256, 0, stream>>>(x, xb);
    k_y12<<<N_NODES / 16, 256, 0, stream>>>(x, Wpre, Y1b, Y2b);
    k_pull<<<N_NODES / 4, 256, 0, stream>>>(eattr, W4, bp, Y1b, Y2b,
                                            rowstart, csr_src, csr_eid, aggB);
    k_node<<<(N_NODES + 127) / 128, 256, 0, stream>>>(Wt, xb, aggB, bpost,
                                                      cnt, avglog, hpostB);
    k_lin<<<(N_NODES + 127) / 128, 256, 0, stream>>>(hpostB, Wlt, blin, out);
}

// Round 6
// 443.357 us; speedup vs baseline: 9.0226x; 1.0217x over previous
//
#include <hip/hip_runtime.h>
#include <hip/hip_bf16.h>
#include <float.h>
#include <math.h>

#define N_NODES 50000
#define N_EDGES 500000
#define D 128
#define ED 10
#define EPS_PNA 1e-5f

typedef __hip_bfloat16 bf16;
typedef unsigned short ushort;
typedef unsigned int uint;
typedef __attribute__((ext_vector_type(8))) short short8;   // 8 bf16 (4 VGPRs)
typedef __attribute__((ext_vector_type(4))) float f32x4;    // MFMA C/D

__device__ __forceinline__ ushort f2bf(float f) {
    __hip_bfloat16 h = __float2bfloat16(f);
    return *reinterpret_cast<ushort*>(&h);
}
__device__ __forceinline__ float bf2f(ushort u) {
    return __uint_as_float(((uint)u) << 16);
}

// ---------------- K0: zero degree histogram ----------------
__global__ void k_init(int* __restrict__ cnt) {
    int i = blockIdx.x * blockDim.x + threadIdx.x;
    if (i < N_NODES) cnt[i] = 0;
}

// ---------------- K1: degree histogram ----------------
__global__ void k_hist(const int* __restrict__ ei, int* __restrict__ cnt) {
    int e = blockIdx.x * blockDim.x + threadIdx.x;
    if (e < N_EDGES) atomicAdd(&cnt[ei[N_EDGES + e]], 1);
}

// ---------------- K2: single-block prefix scan over degrees + avg_log ----------------
__global__ __launch_bounds__(1024) void k_scan(const int* __restrict__ cnt,
                                               int* __restrict__ rowstart,
                                               int* __restrict__ cursor,
                                               float* __restrict__ avglog) {
    const int t = threadIdx.x, lane = t & 63, wv = t >> 6;
    __shared__ int wtot[16], woff[16];
    __shared__ int btot_s;
    __shared__ float lred[16];
    int running = 0;
    float lsum = 0.f;
    for (int base = 0; base < N_NODES; base += 1024) {
        const int idx = base + t;
        int c = (idx < N_NODES) ? cnt[idx] : 0;
        if (idx < N_NODES) lsum += logf((float)c + 1.0f);
        int s = c;
        #pragma unroll
        for (int off = 1; off < 64; off <<= 1) {
            int v = __shfl_up(s, off, 64);
            if (lane >= off) s += v;
        }
        if (lane == 63) wtot[wv] = s;
        __syncthreads();
        if (t == 0) {
            int r = 0;
            #pragma unroll
            for (int i = 0; i < 16; ++i) { woff[i] = r; r += wtot[i]; }
            btot_s = r;
        }
        __syncthreads();
        if (idx < N_NODES) {
            const int excl = running + woff[wv] + (s - c);
            rowstart[idx] = excl;
            cursor[idx] = excl;
        }
        running += btot_s;
        __syncthreads();
    }
    if (t == 0) rowstart[N_NODES] = running;
    float v = lsum;
    for (int off = 32; off > 0; off >>= 1) v += __shfl_down(v, off, 64);
    if (lane == 0) lred[wv] = v;
    __syncthreads();
    if (t == 0) {
        float tt = 0.f;
        for (int i = 0; i < 16; ++i) tt += lred[i];
        avglog[0] = tt * (1.0f / (float)N_NODES);
    }
}

// ---------------- K3: bucket edges into CSR order ----------------
__global__ void k_scatter(const int* __restrict__ ei, int* __restrict__ cursor,
                          int* __restrict__ csr_src, int* __restrict__ csr_eid) {
    int e = blockIdx.x * blockDim.x + threadIdx.x;
    if (e < N_EDGES) {
        const int dst = ei[N_EDGES + e];
        const int pos = atomicAdd(&cursor[dst], 1);
        csr_src[pos] = ei[e];
        csr_eid[pos] = e;
    }
}

// ---------------- K4: fold edge-encoder through W3 ----------------
__global__ __launch_bounds__(128) void k_small(const float* __restrict__ Wee,
                                               const float* __restrict__ bee,
                                               const float* __restrict__ Wpre,
                                               const float* __restrict__ bpre,
                                               float* __restrict__ W4,
                                               float* __restrict__ bp) {
    __shared__ float wee_s[ED * D];
    __shared__ float bee_s[D];
    const int t = threadIdx.x;
    for (int i = t; i < ED * D; i += 128) wee_s[i] = Wee[i];
    bee_s[t] = bee[t];
    __syncthreads();
    float acc[ED];
    #pragma unroll
    for (int r = 0; r < ED; ++r) acc[r] = 0.f;
    float bacc = 0.f;
    for (int k = 0; k < D; ++k) {
        const float w3 = Wpre[(size_t)(2 * D + k) * D + t];
        #pragma unroll
        for (int r = 0; r < ED; ++r) acc[r] += wee_s[r * D + k] * w3;
        bacc += bee_s[k] * w3;
    }
    #pragma unroll
    for (int r = 0; r < ED; ++r) W4[r * D + t] = acc[r];
    bp[t] = bpre[t] + bacc;
}

// ---------------- K5: transpose weight [K][128] fp32 -> [128][K] bf16 ----------------
__global__ void k_prep(const float* __restrict__ src, ushort* __restrict__ dst,
                       int K, int jobs) {
    int id = blockIdx.x * blockDim.x + threadIdx.x;
    if (id >= jobs) return;
    const int col = id & 127;
    const int k0 = (id >> 7) * 8;
    ushort tmp[8];
    #pragma unroll
    for (int r = 0; r < 8; ++r) tmp[r] = f2bf(src[(size_t)(k0 + r) * 128 + col]);
    *(uint4*)(dst + (size_t)col * K + k0) = *(uint4*)tmp;
}

// ---------------- K6: fold Wpost@Wlin -> Wc, routed into transposed bf16 layouts ----------------
// Wc rows: [0,128) -> WxT rows 256..383 (Y0 weights); [128,640) -> WaT slice0 (identity-agg);
// [640,1152) -> WaT slice1 (r1-agg); [1152,1664) -> WaT slice2 (r2-agg).
// Also b_comb = bpost@Wlin + blin.
__global__ __launch_bounds__(256) void k_fold(
    const float* __restrict__ Wpost, const float* __restrict__ bpost,
    const float* __restrict__ Wlin, const float* __restrict__ blin,
    ushort* __restrict__ WxT,     // [384][128]
    ushort* __restrict__ WaT,     // [384][512]
    float* __restrict__ b_comb)
{
    __shared__ float Wl[128 * 128];   // 64 KB fp32
    const int t = threadIdx.x;
    for (int i = t; i < 128 * 128 / 4; i += 256)
        ((float4*)Wl)[i] = ((const float4*)Wlin)[i];
    __syncthreads();
    const int j = t & 127, rp = t >> 7;
    const int kr0 = blockIdx.x * 16 + rp * 8;
    for (int r = 0; r < 8; ++r) {
        const int kr = kr0 + r;
        const float* wrow = Wpost + (size_t)kr * 128;
        float acc = 0.f;
        #pragma unroll 8
        for (int m = 0; m < 128; ++m) acc += wrow[m] * Wl[m * 128 + j];
        const ushort v = f2bf(acc);
        if (kr < 128)       WxT[(256 + j) * 128 + kr] = v;
        else if (kr < 640)  WaT[(size_t)j * 512 + (kr - 128)] = v;
        else if (kr < 1152) WaT[(size_t)(128 + j) * 512 + (kr - 640)] = v;
        else                WaT[(size_t)(256 + j) * 512 + (kr - 1152)] = v;
    }
    if (blockIdx.x == 0 && t < 128) {
        float acc = 0.f;
        #pragma unroll 8
        for (int m = 0; m < 128; ++m) acc += bpost[m] * Wl[m * 128 + t];
        b_comb[t] = acc + blin[t];
    }
}

// ---------------- K7: MFMA x-GEMMs: slice 0 -> Y1b=x@W1, 1 -> Y2b=x@W2, 2 -> Y0b=x@Wc0+b_comb ----------------
__global__ __launch_bounds__(256) void k_xgemm(
    const float* __restrict__ x, const ushort* __restrict__ WxT,
    const float* __restrict__ b_comb,
    ushort* __restrict__ Y1b, ushort* __restrict__ Y2b, ushort* __restrict__ Y0b)
{
    __shared__ __align__(16) ushort Alds[128 * 136];
    __shared__ __align__(16) ushort Hlds[128 * 136];
    const int t = threadIdx.x;
    const int nb = blockIdx.x * 128;
    const int sy = blockIdx.y;

    #pragma unroll
    for (int g = 0; g < 8; ++g) {
        const int idx = t + g * 256;
        const int row = idx >> 4, kk = (idx & 15) * 8;
        *(uint4*)&Alds[row * 136 + kk] =
            *(const uint4*)(WxT + ((size_t)sy * 128 + row) * 128 + kk);
        const int node = nb + row;
        uint4 v = make_uint4(0u, 0u, 0u, 0u);
        if (node < N_NODES) {
            const float4 f0 = *(const float4*)(x + (size_t)node * 128 + kk);
            const float4 f1 = *(const float4*)(x + (size_t)node * 128 + kk + 4);
            __hip_bfloat162 p0 = __float22bfloat162_rn(make_float2(f0.x, f0.y));
            __hip_bfloat162 p1 = __float22bfloat162_rn(make_float2(f0.z, f0.w));
            __hip_bfloat162 p2 = __float22bfloat162_rn(make_float2(f1.x, f1.y));
            __hip_bfloat162 p3 = __float22bfloat162_rn(make_float2(f1.z, f1.w));
            v.x = *(uint*)&p0; v.y = *(uint*)&p1; v.z = *(uint*)&p2; v.w = *(uint*)&p3;
        }
        *(uint4*)&Hlds[row * 136 + kk] = v;
    }
    __syncthreads();

    const int w = t >> 6, l = t & 63;
    const int wr = w >> 1, wc = w & 1;
    const int quad = l >> 4, lr = l & 15;

    f32x4 acc[4][4];
    #pragma unroll
    for (int i = 0; i < 4; ++i)
        #pragma unroll
        for (int j = 0; j < 4; ++j) acc[i][j] = (f32x4){0.f, 0.f, 0.f, 0.f};

    #pragma unroll
    for (int s = 0; s < 4; ++s) {
        short8 av[4], bv[4];
        #pragma unroll
        for (int i = 0; i < 4; ++i)
            av[i] = *(const short8*)&Alds[(wr * 64 + i * 16 + lr) * 136 + s * 32 + quad * 8];
        #pragma unroll
        for (int j = 0; j < 4; ++j)
            bv[j] = *(const short8*)&Hlds[(wc * 64 + j * 16 + lr) * 136 + s * 32 + quad * 8];
        #pragma unroll
        for (int i = 0; i < 4; ++i)
            #pragma unroll
            for (int j = 0; j < 4; ++j)
                acc[i][j] = __builtin_amdgcn_mfma_f32_16x16x32_bf16(av[i], bv[j], acc[i][j], 0, 0, 0);
    }

    ushort* dst = (sy == 0) ? Y1b : (sy == 1) ? Y2b : Y0b;
    #pragma unroll
    for (int i = 0; i < 4; ++i) {
        const int col = wr * 64 + i * 16 + quad * 4;
        float b0 = 0.f, b1 = 0.f, b2 = 0.f, b3 = 0.f;
        if (sy == 2) {
            b0 = b_comb[col]; b1 = b_comb[col + 1];
            b2 = b_comb[col + 2]; b3 = b_comb[col + 3];
        }
        #pragma unroll
        for (int j = 0; j < 4; ++j) {
            const int node = nb + wc * 64 + j * 16 + lr;
            if (node < N_NODES) {
                const f32x4 v = acc[i][j];
                ushort pk[4];
                pk[0] = f2bf(v.x + b0); pk[1] = f2bf(v.y + b1);
                pk[2] = f2bf(v.z + b2); pk[3] = f2bf(v.w + b3);
                *(uint2*)(dst + (size_t)node * 128 + col) = *(uint2*)pk;
            }
        }
    }
}

// ---------------- K8: CSR pull aggregation -> agg bf16 [N][512] ----------------
__global__ __launch_bounds__(256) void k_pull(
    const float* __restrict__ eattr, const float* __restrict__ W4,
    const float* __restrict__ bp, const ushort* __restrict__ Y1b,
    const ushort* __restrict__ Y2b,
    const int* __restrict__ rowstart,
    const int* __restrict__ csr_src, const int* __restrict__ csr_eid,
    ushort* __restrict__ aggB)
{
    __shared__ float2 w4s[ED][64];
    const int t = threadIdx.x;
    for (int i = t; i < ED * 64; i += 256)
        w4s[i >> 6][i & 63] = ((const float2*)W4)[i];
    __syncthreads();

    const int wv = t >> 6, l = t & 63;
    const int n = blockIdx.x * 4 + wv;
    const int r0 = rowstart[n], r1 = rowstart[n + 1];

    float s0 = 0.f, s1 = 0.f, ss0 = 0.f, ss1 = 0.f;
    float mx0 = -FLT_MAX, mx1 = -FLT_MAX, mn0 = FLT_MAX, mn1 = FLT_MAX;
    for (int i = r0; i < r1; ++i) {
        const int src = csr_src[i];
        const int eid = csr_eid[i];
        const float2 y2 = __bfloat1622float2(((const __hip_bfloat162*)Y2b)[(size_t)src * 64 + l]);
        const float2* ea2 = (const float2*)(eattr + (size_t)eid * ED);
        float q0 = 0.f, q1 = 0.f;
        #pragma unroll
        for (int r = 0; r < 5; ++r) {
            const float2 a = ea2[r];
            const float2 wA = w4s[2 * r][l];
            const float2 wB = w4s[2 * r + 1][l];
            q0 += a.x * wA.x + a.y * wB.x;
            q1 += a.x * wA.y + a.y * wB.y;
        }
        const float z0 = y2.x + q0, z1 = y2.y + q1;
        s0 += z0; s1 += z1;
        ss0 += z0 * z0; ss1 += z1 * z1;
        mx0 = fmaxf(mx0, z0); mx1 = fmaxf(mx1, z1);
        mn0 = fminf(mn0, z0); mn1 = fminf(mn1, z1);
    }
    const int d = r1 - r0;
    const float2 bpw = ((const float2*)bp)[l];
    const float2 y1 = __bfloat1622float2(((const __hip_bfloat162*)Y1b)[(size_t)n * 64 + l]);
    float mean0, mean1, vmx0, vmx1, vmn0, vmn1, st0, st1;
    if (d > 0) {
        const float inv = 1.f / (float)d;
        const float mz0 = s0 * inv, mz1 = s1 * inv;
        const float c0 = y1.x + bpw.x, c1 = y1.y + bpw.y;
        mean0 = mz0 + c0; mean1 = mz1 + c1;
        st0 = sqrtf(fmaxf(ss0 * inv - mz0 * mz0, 0.f) + EPS_PNA);
        st1 = sqrtf(fmaxf(ss1 * inv - mz1 * mz1, 0.f) + EPS_PNA);
        vmx0 = mx0 + c0; vmx1 = mx1 + c1;
        vmn0 = mn0 + c0; vmn1 = mn1 + c1;
    } else {
        mean0 = mean1 = 0.f;
        vmx0 = vmx1 = vmn0 = vmn1 = 0.f;
        st0 = st1 = sqrtf(EPS_PNA);
    }
    __hip_bfloat162* aggv = (__hip_bfloat162*)aggB;
    const size_t b0 = (size_t)n * 256;
    aggv[b0 + l]       = __float22bfloat162_rn(make_float2(mean0, mean1));
    aggv[b0 + 64 + l]  = __float22bfloat162_rn(make_float2(vmx0, vmx1));
    aggv[b0 + 128 + l] = __float22bfloat162_rn(make_float2(vmn0, vmn1));
    aggv[b0 + 192 + l] = __float22bfloat162_rn(make_float2(st0, st1));
}

// ---------------- K9: MFMA agg-GEMM with 3 in-register slices ----------------
// out[n][col] = Y0b[n][col] + G0 + r1[n]*G1 + r2[n]*G2,  G_s = agg @ Wc_s (K=512).
// 64 nodes/block, 128 cols, slice loop inside; grid 782.
__global__ __launch_bounds__(256) void k_agg(
    const ushort* __restrict__ aggB,  // [N][512] bf16
    const ushort* __restrict__ WaT,   // [384][512] bf16
    const ushort* __restrict__ Y0b,   // [N][128] bf16
    const int* __restrict__ cnt, const float* __restrict__ avglog,
    float* __restrict__ out)
{
    __shared__ __align__(16) ushort Alds[128 * 72];
    __shared__ __align__(16) ushort Hlds[64 * 72];
    __shared__ float r1s[64], r2s[64];

    const int t = threadIdx.x;
    const int nb = blockIdx.x * 64;
    if (t < 64) {
        const int node = nb + t;
        float deg = 1.f;
        if (node < N_NODES) deg = fmaxf((float)cnt[node], 1.f);
        const float sl = logf(deg + 1.f);
        const float al = avglog[0];
        r1s[t] = sl / al;
        r2s[t] = al / sl;
    }

    const int w = t >> 6, l = t & 63;
    const int wr = w >> 1, wc = w & 1;   // wr: col half (64), wc: node half (32)
    const int quad = l >> 4, lr = l & 15;

    f32x4 comb[4][2];
    #pragma unroll
    for (int i = 0; i < 4; ++i)
        #pragma unroll
        for (int j = 0; j < 2; ++j) comb[i][j] = (f32x4){0.f, 0.f, 0.f, 0.f};

    for (int sl = 0; sl < 3; ++sl) {
        f32x4 acc[4][2];
        #pragma unroll
        for (int i = 0; i < 4; ++i)
            #pragma unroll
            for (int j = 0; j < 2; ++j) acc[i][j] = (f32x4){0.f, 0.f, 0.f, 0.f};

        for (int kc = 0; kc < 8; ++kc) {
            const int k0 = kc * 64;
            __syncthreads();
            #pragma unroll
            for (int g = 0; g < 4; ++g) {      // A: 128 rows x 64 k
                const int idx = t + g * 256;
                const int row = idx >> 3, kk = (idx & 7) * 8;
                *(uint4*)&Alds[row * 72 + kk] =
                    *(const uint4*)(WaT + ((size_t)(sl * 128 + row)) * 512 + k0 + kk);
            }
            #pragma unroll
            for (int g = 0; g < 2; ++g) {      // H: 64 rows x 64 k
                const int idx = t + g * 256;
                const int row = idx >> 3, kk = (idx & 7) * 8;
                const int node = nb + row;
                uint4 v = make_uint4(0u, 0u, 0u, 0u);
                if (node < N_NODES)
                    v = *(const uint4*)(aggB + (size_t)node * 512 + k0 + kk);
                *(uint4*)&Hlds[row * 72 + kk] = v;
            }
            __syncthreads();
            #pragma unroll
            for (int s = 0; s < 2; ++s) {
                short8 av[4], bv[2];
                #pragma unroll
                for (int i = 0; i < 4; ++i)
                    av[i] = *(const short8*)&Alds[(wr * 64 + i * 16 + lr) * 72 + s * 32 + quad * 8];
                #pragma unroll
                for (int j = 0; j < 2; ++j)
                    bv[j] = *(const short8*)&Hlds[(wc * 32 + j * 16 + lr) * 72 + s * 32 + quad * 8];
                #pragma unroll
                for (int i = 0; i < 4; ++i)
                    #pragma unroll
                    for (int j = 0; j < 2; ++j)
                        acc[i][j] = __builtin_amdgcn_mfma_f32_16x16x32_bf16(av[i], bv[j], acc[i][j], 0, 0, 0);
            }
        }
        // fold slice into comb with per-node scale
        #pragma unroll
        for (int j = 0; j < 2; ++j) {
            const int nl = wc * 32 + j * 16 + lr;
            const float r = (sl == 0) ? 1.f : (sl == 1) ? r1s[nl] : r2s[nl];
            #pragma unroll
            for (int i = 0; i < 4; ++i) {
                comb[i][j].x += r * acc[i][j].x;
                comb[i][j].y += r * acc[i][j].y;
                comb[i][j].z += r * acc[i][j].z;
                comb[i][j].w += r * acc[i][j].w;
            }
        }
    }

    #pragma unroll
    for (int i = 0; i < 4; ++i) {
        const int col = wr * 64 + i * 16 + quad * 4;
        #pragma unroll
        for (int j = 0; j < 2; ++j) {
            const int node = nb + wc * 32 + j * 16 + lr;
            if (node < N_NODES) {
                const uint2 y0 = *(const uint2*)(Y0b + (size_t)node * 128 + col);
                const ushort* yp = (const ushort*)&y0;
                const f32x4 v = comb[i][j];
                *(float4*)(out + (size_t)node * 128 + col) =
                    make_float4(v.x + bf2f(yp[0]), v.y + bf2f(yp[1]),
                                v.z + bf2f(yp[2]), v.w + bf2f(yp[3]));
            }
        }
    }
}

extern "C" void kernel_launch(void* const* d_in, const int* in_sizes, int n_in,
                              void* d_out, int out_size, void* d_ws, size_t ws_size,
                              hipStream_t stream) {
    const float* x     = (const float*)d_in[0];
    const float* eattr = (const float*)d_in[1];
    const float* Wee   = (const float*)d_in[2];
    const float* bee   = (const float*)d_in[3];
    const float* Wpre  = (const float*)d_in[4];
    const float* bpre  = (const float*)d_in[5];
    const float* Wpost = (const float*)d_in[6];
    const float* bpost = (const float*)d_in[7];
    const float* Wlin  = (const float*)d_in[8];
    const float* blin  = (const float*)d_in[9];
    const int*   ei    = (const int*)d_in[10];
    float* out = (float*)d_out;

    // workspace layout (~94.5 MB; ws_size >= 102.6 MB proven by round-2 run)
    ushort* aggB = (ushort*)d_ws;                         // N*512 bf16 (51.2 MB)
    ushort* Y1b  = aggB + (size_t)N_NODES * 512;          // N*128 bf16
    ushort* Y2b  = Y1b  + (size_t)N_NODES * 128;          // N*128 bf16
    ushort* Y0b  = Y2b  + (size_t)N_NODES * 128;          // N*128 bf16
    ushort* WxT  = Y0b  + (size_t)N_NODES * 128;          // 384*128 bf16
    ushort* WaT  = WxT + 384 * 128;                       // 384*512 bf16
    float*  W4   = (float*)(WaT + 384 * 512);             // ED*D fp32
    float*  bp   = W4 + ED * D;                           // 128
    float*  b_comb = bp + D;                              // 128
    float*  avglog = b_comb + D;                          // 1 (+3 pad)
    int*   cnt      = (int*)(avglog + 4);
    int*   rowstart = cnt + N_NODES;
    int*   cursor   = rowstart + N_NODES + 2;
    int*   csr_src  = cursor + N_NODES;
    int*   csr_eid  = csr_src + N_EDGES;

    k_init<<<(N_NODES + 255) / 256, 256, 0, stream>>>(cnt);
    k_hist<<<(N_EDGES + 255) / 256, 256, 0, stream>>>(ei, cnt);
    k_scan<<<1, 1024, 0, stream>>>(cnt, rowstart, cursor, avglog);
    k_scatter<<<(N_EDGES + 255) / 256, 256, 0, stream>>>(ei, cursor, csr_src, csr_eid);
    k_small<<<1, 128, 0, stream>>>(Wee, bee, Wpre, bpre, W4, bp);
    k_prep<<<8, 256, 0, stream>>>(Wpre, WxT, 128, 2048);                    // W1^T
    k_prep<<<8, 256, 0, stream>>>(Wpre + 128 * 128, WxT + 128 * 128, 128, 2048); // W2^T
    k_fold<<<104, 256, 0, stream>>>(Wpost, bpost, Wlin, blin, WxT, WaT, b_comb);
    k_xgemm<<<dim3((N_NODES + 127) / 128, 3), 256, 0, stream>>>(x, WxT, b_comb,
                                                                Y1b, Y2b, Y0b);
    k_pull<<<N_NODES / 4, 256, 0, stream>>>(eattr, W4, bp, Y1b, Y2b,
                                            rowstart, csr_src, csr_eid, aggB);
    k_agg<<<(N_NODES + 63) / 64, 256, 0, stream>>>(aggB, WaT, Y0b, cnt, avglog, out);
}